// Round 1
// baseline (519.645 us; speedup 1.0000x reference)
//
#include <hip/hip_runtime.h>
#include <stdint.h>
#include <stddef.h>

typedef unsigned short u16;
typedef __attribute__((ext_vector_type(8))) short short8;
typedef __attribute__((ext_vector_type(4))) float f32x4;

constexpr int B_ = 8, S_ = 1024, HID_ = 1024, NH_ = 16, HD_ = 64;

__device__ __forceinline__ u16 f2b(float f) {
  unsigned int u = __builtin_bit_cast(unsigned int, f);
  u += 0x7fff + ((u >> 16) & 1);   // RNE
  return (u16)(u >> 16);
}
__device__ __forceinline__ float b2f(u16 s) {
  unsigned int u = ((unsigned int)s) << 16;
  return __builtin_bit_cast(float, u);
}
__device__ __forceinline__ void llds16(const void* g, void* l) {
  __builtin_amdgcn_global_load_lds((__attribute__((address_space(1))) void*)g,
                                   (__attribute__((address_space(3))) void*)l, 16, 0, 0);
}

// ---------------- fp32 -> bf16 conversions ----------------
__global__ __launch_bounds__(256) void prep_cvt(
    const float* __restrict__ x, const float* __restrict__ wqkv,
    const float* __restrict__ wout, u16* __restrict__ xb,
    u16* __restrict__ wqkvb, u16* __restrict__ woutb) {
  const int NX4 = B_ * S_ * HID_ / 4, NW14 = 3 * HID_ * HID_ / 4, NW24 = HID_ * HID_ / 4;
  const int tot = NX4 + NW14 + NW24;
  for (int i = blockIdx.x * blockDim.x + threadIdx.x; i < tot; i += gridDim.x * blockDim.x) {
    const float4* s; u16* d; int j;
    if (i < NX4)              { s = (const float4*)x;    d = xb;    j = i; }
    else if (i < NX4 + NW14)  { s = (const float4*)wqkv; d = wqkvb; j = i - NX4; }
    else                      { s = (const float4*)wout; d = woutb; j = i - NX4 - NW14; }
    float4 v = s[j];
    ushort4 o; o.x = f2b(v.x); o.y = f2b(v.y); o.z = f2b(v.z); o.w = f2b(v.w);
    *(ushort4*)(d + 4 * (size_t)j) = o;
  }
}

__global__ __launch_bounds__(256) void rel_sum(
    const float* __restrict__ a, const float* __restrict__ b, u16* __restrict__ relb) {
  const int N4 = NH_ * S_ * S_ / 4;
  for (int i = blockIdx.x * blockDim.x + threadIdx.x; i < N4; i += gridDim.x * blockDim.x) {
    float4 va = ((const float4*)a)[i];
    float4 vb = ((const float4*)b)[i];
    ushort4 o;
    o.x = f2b(va.x + vb.x); o.y = f2b(va.y + vb.y);
    o.z = f2b(va.z + vb.z); o.w = f2b(va.w + vb.w);
    *(ushort4*)(relb + 4 * (size_t)i) = o;
  }
}

// ---------------- QKV projection GEMM (M=8192,N=3072,K=1024, NT) ----------------
__global__ __launch_bounds__(256) void gemm_qkv(
    const u16* __restrict__ A, const u16* __restrict__ Bw,
    const float* __restrict__ qbias, const float* __restrict__ vbias,
    u16* __restrict__ Qb, u16* __restrict__ Kb, u16* __restrict__ Vb) {
  constexpr int K = HID_;
  __shared__ u16 As[128 * 32];
  __shared__ u16 Bs[128 * 32];
  const int m0 = blockIdx.x * 128, n0 = blockIdx.y * 128;
  const int t = threadIdx.x, lane = t & 63, wv = t >> 6;
  const int wr = wv >> 1, wc = wv & 1, ln = lane & 15, q8 = lane >> 4;

  f32x4 acc[4][4] = {};

  for (int kt = 0; kt < K / 32; ++kt) {
    const int k0 = kt * 32;
#pragma unroll
    for (int c = 0; c < 2; ++c) {
      int idx = c * 256 + t;
      int row = idx >> 2, cc = (idx & 3) * 8;
      llds16(A  + (size_t)(m0 + row) * K + k0 + cc, As + (size_t)(c * 256 + wv * 64) * 8);
      llds16(Bw + (size_t)(n0 + row) * K + k0 + cc, Bs + (size_t)(c * 256 + wv * 64) * 8);
    }
    __syncthreads();
    short8 af[4], bf[4];
#pragma unroll
    for (int mi = 0; mi < 4; ++mi)
      af[mi] = *(const short8*)(As + (wr * 64 + mi * 16 + ln) * 32 + q8 * 8);
#pragma unroll
    for (int ni = 0; ni < 4; ++ni)
      bf[ni] = *(const short8*)(Bs + (wc * 64 + ni * 16 + ln) * 32 + q8 * 8);
#pragma unroll
    for (int mi = 0; mi < 4; ++mi)
#pragma unroll
      for (int ni = 0; ni < 4; ++ni)
        acc[mi][ni] = __builtin_amdgcn_mfma_f32_16x16x32_bf16(af[mi], bf[ni], acc[mi][ni], 0, 0, 0);
    __syncthreads();
  }

  const int sec = n0 >> 10;  // block-uniform: 0=Q 1=K 2=V
#pragma unroll
  for (int mi = 0; mi < 4; ++mi)
#pragma unroll
    for (int ni = 0; ni < 4; ++ni) {
      const int n = n0 + wc * 64 + ni * 16 + ln;
      const int nn = n & 1023, hh = nn >> 6, dd = nn & 63;
      const int mb = m0 + wr * 64 + mi * 16 + q8 * 4;
#pragma unroll
      for (int r = 0; r < 4; ++r) {
        const int m = mb + r, bb = m >> 10, ss = m & 1023;
        size_t dst = ((size_t)(bb * NH_ + hh) * S_ + ss) * HD_ + dd;
        float v = acc[mi][ni][r];
        if (sec == 0)      Qb[dst] = f2b((v + qbias[nn]) * 0.125f);
        else if (sec == 1) Kb[dst] = f2b(v);
        else               Vb[dst] = f2b(v + vbias[nn]);
      }
    }
}

// ---------------- V -> V^T  ([B,NH,S,HD] -> [B,NH,HD,S]) ----------------
__global__ __launch_bounds__(256) void transpose_v(
    const u16* __restrict__ Vb, u16* __restrict__ Vtb) {
  __shared__ u16 tile[64][72];
  const int st = blockIdx.x * 64, bh = blockIdx.y;
  const int t = threadIdx.x;
#pragma unroll
  for (int i = 0; i < 2; ++i) {
    int idx = i * 256 + t, row = idx >> 3, c8 = (idx & 7) * 8;
    *(short8*)(&tile[row][c8]) = *(const short8*)(Vb + ((size_t)bh * S_ + st + row) * HD_ + c8);
  }
  __syncthreads();
#pragma unroll
  for (int i = 0; i < 2; ++i) {
    int idx = i * 256 + t, d = idx >> 3, c8 = (idx & 7) * 8;
    short8 v;
#pragma unroll
    for (int j = 0; j < 8; ++j) v[j] = (short)tile[c8 + j][d];
    *(short8*)(Vtb + ((size_t)bh * HD_ + d) * S_ + st + c8) = v;
  }
}

// ---------------- flash attention with rel bias ----------------
__global__ __launch_bounds__(256) void flash_attn(
    const u16* __restrict__ Qb, const u16* __restrict__ Kb,
    const u16* __restrict__ Vtb, const u16* __restrict__ relb,
    const unsigned char* __restrict__ mask, u16* __restrict__ ctxb) {
  const int qt = blockIdx.x, h = blockIdx.y, b = blockIdx.z;
  const int bh = b * NH_ + h, q0 = qt * 128;
  const int t = threadIdx.x, lane = t & 63, wv = t >> 6;
  const int ln = lane & 15, q8 = lane >> 4;

  __shared__ u16 Ks[128 * 72];    // [k][64+8]
  __shared__ u16 Vts[64 * 136];   // [d][128+8]
  __shared__ u16 Ps[4][32 * 136]; // per-wave [q][128+8]

  // Q fragments live in registers (A-operand layout)
  short8 qf[2][2];
#pragma unroll
  for (int rf = 0; rf < 2; ++rf)
#pragma unroll
    for (int kc = 0; kc < 2; ++kc)
      qf[rf][kc] = *(const short8*)(Qb + ((size_t)bh * S_ + q0 + wv * 32 + rf * 16 + ln) * HD_ + kc * 32 + q8 * 8);

  f32x4 Oa[2][4] = {};
  float mrow[2][4], lrow[2][4];
#pragma unroll
  for (int rf = 0; rf < 2; ++rf)
#pragma unroll
    for (int r = 0; r < 4; ++r) { mrow[rf][r] = -1e30f; lrow[rf][r] = 0.f; }

  for (int kt = 0; kt < 8; ++kt) {
    const int k0 = kt * 128;
    __syncthreads();
#pragma unroll
    for (int i = 0; i < 4; ++i) {  // stage K tile [128][64]
      int idx = i * 256 + t, row = idx >> 3, c8 = (idx & 7) * 8;
      *(short8*)(Ks + row * 72 + c8) =
          *(const short8*)(Kb + ((size_t)bh * S_ + k0 + row) * HD_ + c8);
    }
#pragma unroll
    for (int i = 0; i < 4; ++i) {  // stage V^T tile [64][128]
      int idx = i * 256 + t, row = idx >> 4, c8 = (idx & 15) * 8;
      *(short8*)(Vts + row * 136 + c8) =
          *(const short8*)(Vtb + ((size_t)bh * HD_ + row) * S_ + k0 + c8);
    }
    __syncthreads();

    // scores acc initialized with rel bias + mask
    f32x4 sc[2][8];
#pragma unroll
    for (int rf = 0; rf < 2; ++rf) {
      const int qb_ = q0 + wv * 32 + rf * 16 + q8 * 4;
#pragma unroll
      for (int cf = 0; cf < 8; ++cf) {
        const int k = k0 + cf * 16 + ln;
        const float mb = mask[b * S_ + k] ? -1e30f : 0.f;
        f32x4 v;
#pragma unroll
        for (int r = 0; r < 4; ++r)
          v[r] = b2f(relb[((size_t)h * S_ + qb_ + r) * S_ + k]) + mb;
        sc[rf][cf] = v;
      }
    }
    // QK^T
#pragma unroll
    for (int kc = 0; kc < 2; ++kc) {
      short8 kf[8];
#pragma unroll
      for (int cf = 0; cf < 8; ++cf)
        kf[cf] = *(const short8*)(Ks + (cf * 16 + ln) * 72 + kc * 32 + q8 * 8);
#pragma unroll
      for (int rf = 0; rf < 2; ++rf)
#pragma unroll
        for (int cf = 0; cf < 8; ++cf)
          sc[rf][cf] = __builtin_amdgcn_mfma_f32_16x16x32_bf16(qf[rf][kc], kf[cf], sc[rf][cf], 0, 0, 0);
    }

    // online softmax update
#pragma unroll
    for (int rf = 0; rf < 2; ++rf)
#pragma unroll
      for (int r = 0; r < 4; ++r) {
        float mx = sc[rf][0][r];
#pragma unroll
        for (int cf = 1; cf < 8; ++cf) mx = fmaxf(mx, sc[rf][cf][r]);
#pragma unroll
        for (int off = 1; off < 16; off <<= 1) mx = fmaxf(mx, __shfl_xor(mx, off, 64));
        const float mnew = fmaxf(mrow[rf][r], mx);
        const float alpha = __expf(mrow[rf][r] - mnew);
        mrow[rf][r] = mnew;
        float rs = 0.f;
#pragma unroll
        for (int cf = 0; cf < 8; ++cf) {
          float p = __expf(sc[rf][cf][r] - mnew);
          sc[rf][cf][r] = p;
          rs += p;
        }
#pragma unroll
        for (int off = 1; off < 16; off <<= 1) rs += __shfl_xor(rs, off, 64);
        lrow[rf][r] = lrow[rf][r] * alpha + rs;
#pragma unroll
        for (int df = 0; df < 4; ++df) Oa[rf][df][r] *= alpha;
      }

    // P: C-layout -> A-layout via wave-private LDS
#pragma unroll
    for (int rf = 0; rf < 2; ++rf)
#pragma unroll
      for (int cf = 0; cf < 8; ++cf)
#pragma unroll
        for (int r = 0; r < 4; ++r)
          Ps[wv][(rf * 16 + q8 * 4 + r) * 136 + cf * 16 + ln] = f2b(sc[rf][cf][r]);

    // PV
#pragma unroll
    for (int kvc = 0; kvc < 4; ++kvc) {
      short8 pf[2], vf[4];
#pragma unroll
      for (int rf = 0; rf < 2; ++rf)
        pf[rf] = *(const short8*)(&Ps[wv][(rf * 16 + ln) * 136 + kvc * 32 + q8 * 8]);
#pragma unroll
      for (int df = 0; df < 4; ++df)
        vf[df] = *(const short8*)(Vts + (df * 16 + ln) * 136 + kvc * 32 + q8 * 8);
#pragma unroll
      for (int rf = 0; rf < 2; ++rf)
#pragma unroll
        for (int df = 0; df < 4; ++df)
          Oa[rf][df] = __builtin_amdgcn_mfma_f32_16x16x32_bf16(pf[rf], vf[df], Oa[rf][df], 0, 0, 0);
    }
  }

  // epilogue: O /= l, write ctx [B,S,NH*HD]
#pragma unroll
  for (int rf = 0; rf < 2; ++rf)
#pragma unroll
    for (int r = 0; r < 4; ++r) {
      const float inv = 1.f / lrow[rf][r];
      const int q = q0 + wv * 32 + rf * 16 + q8 * 4 + r;
#pragma unroll
      for (int df = 0; df < 4; ++df)
        ctxb[((size_t)(b * S_ + q)) * HID_ + h * HD_ + df * 16 + ln] = f2b(Oa[rf][df][r] * inv);
    }
}

// ---------------- output projection GEMM (M=8192,N=1024,K=1024, NT) ----------------
__global__ __launch_bounds__(256) void gemm_out(
    const u16* __restrict__ A, const u16* __restrict__ Bw,
    const float* __restrict__ bout, const float* __restrict__ x,
    u16* __restrict__ hb) {
  constexpr int K = HID_;
  __shared__ u16 As[128 * 32];
  __shared__ u16 Bs[128 * 32];
  const int m0 = blockIdx.x * 128, n0 = blockIdx.y * 128;
  const int t = threadIdx.x, lane = t & 63, wv = t >> 6;
  const int wr = wv >> 1, wc = wv & 1, ln = lane & 15, q8 = lane >> 4;

  f32x4 acc[4][4] = {};

  for (int kt = 0; kt < K / 32; ++kt) {
    const int k0 = kt * 32;
#pragma unroll
    for (int c = 0; c < 2; ++c) {
      int idx = c * 256 + t;
      int row = idx >> 2, cc = (idx & 3) * 8;
      llds16(A  + (size_t)(m0 + row) * K + k0 + cc, As + (size_t)(c * 256 + wv * 64) * 8);
      llds16(Bw + (size_t)(n0 + row) * K + k0 + cc, Bs + (size_t)(c * 256 + wv * 64) * 8);
    }
    __syncthreads();
    short8 af[4], bf[4];
#pragma unroll
    for (int mi = 0; mi < 4; ++mi)
      af[mi] = *(const short8*)(As + (wr * 64 + mi * 16 + ln) * 32 + q8 * 8);
#pragma unroll
    for (int ni = 0; ni < 4; ++ni)
      bf[ni] = *(const short8*)(Bs + (wc * 64 + ni * 16 + ln) * 32 + q8 * 8);
#pragma unroll
    for (int mi = 0; mi < 4; ++mi)
#pragma unroll
      for (int ni = 0; ni < 4; ++ni)
        acc[mi][ni] = __builtin_amdgcn_mfma_f32_16x16x32_bf16(af[mi], bf[ni], acc[mi][ni], 0, 0, 0);
    __syncthreads();
  }

#pragma unroll
  for (int mi = 0; mi < 4; ++mi)
#pragma unroll
    for (int ni = 0; ni < 4; ++ni) {
      const int n = n0 + wc * 64 + ni * 16 + ln;
      const int mb = m0 + wr * 64 + mi * 16 + q8 * 4;
#pragma unroll
      for (int r = 0; r < 4; ++r) {
        const int m = mb + r;
        float v = acc[mi][ni][r] + bout[n] + x[(size_t)m * HID_ + n];
        hb[(size_t)m * HID_ + n] = f2b(v);
      }
    }
}

// ---------------- LayerNorm, one wave per row ----------------
__global__ __launch_bounds__(256) void ln_kernel(
    const u16* __restrict__ hb, const float* __restrict__ gamma,
    const float* __restrict__ beta, float* __restrict__ out) {
  const int lane = threadIdx.x & 63, wv = threadIdx.x >> 6;
  const int row = blockIdx.x * 4 + wv;
  const u16* hr = hb + (size_t)row * HID_;
  float v[16];
  short8 a = *(const short8*)(hr + lane * 16);
  short8 c = *(const short8*)(hr + lane * 16 + 8);
#pragma unroll
  for (int j = 0; j < 8; ++j) { v[j] = b2f((u16)a[j]); v[8 + j] = b2f((u16)c[j]); }
  float sum = 0.f, sq = 0.f;
#pragma unroll
  for (int j = 0; j < 16; ++j) { sum += v[j]; sq += v[j] * v[j]; }
#pragma unroll
  for (int off = 1; off < 64; off <<= 1) {
    sum += __shfl_xor(sum, off, 64);
    sq  += __shfl_xor(sq, off, 64);
  }
  const float mu = sum * (1.f / HID_);
  const float var = sq * (1.f / HID_) - mu * mu;
  const float inv = 1.f / sqrtf(var + 1e-12f);
#pragma unroll
  for (int j = 0; j < 16; ++j) {
    const int n = lane * 16 + j;
    out[(size_t)row * HID_ + n] = (v[j] - mu) * inv * gamma[n] + beta[n];
  }
}

extern "C" void kernel_launch(void* const* d_in, const int* in_sizes, int n_in,
                              void* d_out, int out_size, void* d_ws, size_t ws_size,
                              hipStream_t stream) {
  (void)in_sizes; (void)n_in; (void)out_size; (void)ws_size;
  const float* x     = (const float*)d_in[0];
  const unsigned char* mask = (const unsigned char*)d_in[1];  // all-False in harness input
  const float* relp  = (const float*)d_in[2];
  const float* rel2  = (const float*)d_in[3];
  const float* wqkv  = (const float*)d_in[4];
  const float* qbias = (const float*)d_in[5];
  const float* vbias = (const float*)d_in[6];
  const float* wout  = (const float*)d_in[7];
  const float* bout  = (const float*)d_in[8];
  const float* gamma = (const float*)d_in[9];
  const float* beta  = (const float*)d_in[10];
  float* out = (float*)d_out;

  char* ws = (char*)d_ws;
  const size_t MB = (size_t)1 << 20;
  u16* xb    = (u16*)(ws + 0 * MB);    // 16 MB (reused as Vtb after gemm_qkv)
  u16* wqkvb = (u16*)(ws + 16 * MB);   // 6 MB
  u16* woutb = (u16*)(ws + 22 * MB);   // 2 MB
  u16* relb  = (u16*)(ws + 24 * MB);   // 32 MB
  u16* Qb    = (u16*)(ws + 56 * MB);   // 16 MB
  u16* Kb    = (u16*)(ws + 72 * MB);   // 16 MB
  u16* Vb    = (u16*)(ws + 88 * MB);   // 16 MB
  u16* ctxb  = (u16*)(ws + 104 * MB);  // 16 MB
  u16* hb    = (u16*)(ws + 120 * MB);  // 16 MB  -> 136 MB total
  u16* Vtb   = xb;                     // xb dead after gemm_qkv (stream-ordered)

  prep_cvt<<<1024, 256, 0, stream>>>(x, wqkv, wout, xb, wqkvb, woutb);
  rel_sum<<<4096, 256, 0, stream>>>(relp, rel2, relb);
  gemm_qkv<<<dim3(64, 24), 256, 0, stream>>>(xb, wqkvb, qbias, vbias, Qb, Kb, Vb);
  transpose_v<<<dim3(16, 128), 256, 0, stream>>>(Vb, Vtb);
  flash_attn<<<dim3(8, 16, 8), 256, 0, stream>>>(Qb, Kb, Vtb, relb, mask, ctxb);
  gemm_out<<<dim3(64, 8), 256, 0, stream>>>(ctxb, woutb, bout, x, hb);
  ln_kernel<<<2048, 256, 0, stream>>>(hb, gamma, beta, out);
}